// Round 1
// baseline (159.903 us; speedup 1.0000x reference)
//
#include <hip/hip_runtime.h>

// RoIAlign (torchvision-style, aligned=false) for MI355X.
// feature: (N=4, C=256, H=200, W=200) f32, rois: (K,5) f32 as [b, y1, x1, y2, x2]
// output: (K, C, 7, 7) f32.
// One thread per output element, pw fastest -> coalesced stores; adjacent
// lanes gather adjacent pixels in one channel plane -> good cache-line reuse.

constexpr int POOLED = 7;
constexpr int SR = 2;            // sampling ratio
constexpr int C_DIM = 256;
constexpr int H_DIM = 200;
constexpr int W_DIM = 200;
constexpr float SCALE = 0.25f;

__global__ __launch_bounds__(256) void roi_align_kernel(
    const float* __restrict__ feat,
    const float* __restrict__ rois,
    float* __restrict__ out,
    int total)
{
    int idx = blockIdx.x * 256 + threadIdx.x;
    if (idx >= total) return;

    int pw = idx % POOLED;
    int t  = idx / POOLED;
    int ph = t % POOLED;
    t /= POOLED;
    int c = t % C_DIM;
    int k = t / C_DIM;

    // raw rois columns: [batch, y1, x1, y2, x2]; x axis -> W, y axis -> H
    const float* r = rois + (size_t)k * 5;
    int   n  = (int)r[0];
    float y1 = r[1] * SCALE;
    float x1 = r[2] * SCALE;
    float y2 = r[3] * SCALE;
    float x2 = r[4] * SCALE;

    float roi_w = fmaxf(x2 - x1, 1.0f);
    float roi_h = fmaxf(y2 - y1, 1.0f);
    float bw = roi_w * (1.0f / POOLED);
    float bh = roi_h * (1.0f / POOLED);

    const float* fp = feat + ((size_t)n * C_DIM + c) * (size_t)(H_DIM * W_DIM);

    // 2 distinct x sample coords and 2 distinct y sample coords per thread
    int   xlo[SR], xhi[SR], yrow0[SR], yrow1[SR];
    float lx[SR], hx[SR], ly[SR], hy[SR];

    #pragma unroll
    for (int i = 0; i < SR; ++i) {
        // x axis
        {
            float cd = x1 + (pw + (i + 0.5f) * (1.0f / SR)) * bw;
            float valid = (cd >= -1.0f && cd <= (float)W_DIM) ? 1.0f : 0.0f;
            float cc = fmaxf(cd, 0.0f);
            int   c0 = min((int)cc, W_DIM - 1);   // floor of non-negative
            int   c1 = min(c0 + 1, W_DIM - 1);
            float l  = (c0 >= W_DIM - 1) ? 0.0f : cc - (float)c0;
            lx[i] = l * valid;
            hx[i] = (1.0f - l) * valid;
            xlo[i] = c0;
            xhi[i] = c1;
        }
        // y axis
        {
            float cd = y1 + (ph + (i + 0.5f) * (1.0f / SR)) * bh;
            float valid = (cd >= -1.0f && cd <= (float)H_DIM) ? 1.0f : 0.0f;
            float cc = fmaxf(cd, 0.0f);
            int   c0 = min((int)cc, H_DIM - 1);
            int   c1 = min(c0 + 1, H_DIM - 1);
            float l  = (c0 >= H_DIM - 1) ? 0.0f : cc - (float)c0;
            ly[i] = l * valid;
            hy[i] = (1.0f - l) * valid;
            yrow0[i] = c0 * W_DIM;
            yrow1[i] = c1 * W_DIM;
        }
    }

    float acc = 0.0f;
    #pragma unroll
    for (int iy = 0; iy < SR; ++iy) {
        #pragma unroll
        for (int ix = 0; ix < SR; ++ix) {
            float v00 = fp[yrow0[iy] + xlo[ix]];
            float v01 = fp[yrow0[iy] + xhi[ix]];
            float v10 = fp[yrow1[iy] + xlo[ix]];
            float v11 = fp[yrow1[iy] + xhi[ix]];
            acc += hy[iy] * (hx[ix] * v00 + lx[ix] * v01)
                 + ly[iy] * (hx[ix] * v10 + lx[ix] * v11);
        }
    }

    out[idx] = acc * (1.0f / (SR * SR));
}

extern "C" void kernel_launch(void* const* d_in, const int* in_sizes, int n_in,
                              void* d_out, int out_size, void* d_ws, size_t ws_size,
                              hipStream_t stream) {
    const float* feature = (const float*)d_in[0];
    const float* rois    = (const float*)d_in[1];
    float* out = (float*)d_out;

    int K = in_sizes[1] / 5;
    int total = K * C_DIM * POOLED * POOLED;   // == out_size

    int blocks = (total + 255) / 256;
    roi_align_kernel<<<blocks, 256, 0, stream>>>(feature, rois, out, total);
}